// Round 3
// baseline (253.168 us; speedup 1.0000x reference)
//
#include <hip/hip_runtime.h>

// predicted (S,B,H,W) f32, target (B,S,H,W) f32, output (S,B,H,W) f32.
#define SS 10
#define BB 8
#define HH 512
#define WW 512
// Sentinel for out-of-image candidates: loss |t - BIGV| always loses to any
// valid candidate (inputs are N(0,1)/U(0,1)), so no validity logic needed in
// the argmin loop. Finite so no NaN from inf-inf can arise.
#define BIGV 3.0e38f

__device__ __forceinline__ void load_row(float dst[6], const float* __restrict__ rp,
                                         int wb, bool rv) {
    // rp points at a VALID in-bounds row start + wb (row clamped by caller).
    float4 c4 = *reinterpret_cast<const float4*>(rp);
    float lft = (wb > 0)      ? rp[-1] : BIGV;   // w-1 halo (in-bounds when wb>0)
    float rgt = (wb + 4 < WW) ? rp[4]  : BIGV;   // w+4 halo
    dst[0] = rv ? lft  : BIGV;
    dst[1] = rv ? c4.x : BIGV;
    dst[2] = rv ? c4.y : BIGV;
    dst[3] = rv ? c4.z : BIGV;
    dst[4] = rv ? c4.w : BIGV;
    dst[5] = rv ? rgt  : BIGV;
}

__global__ __launch_bounds__(256) void shiftpred_kernel(
    const float* __restrict__ pred,   // (S,B,H,W)
    const float* __restrict__ targ,   // (B,S,H,W)
    float* __restrict__ out)          // (S,B,H,W)
{
    const int W4 = WW / 4;                        // 128 quads per row
    const int H4 = HH / 4;                        // 128 row-tiles per plane
    int tid = blockIdx.x * blockDim.x + threadIdx.x;

    int wq = tid & (W4 - 1);
    int hq = (tid >> 7) & (H4 - 1);
    int sb = tid >> 14;
    if (sb >= SS * BB) return;

    int s = sb >> 3;
    int b = sb & 7;
    int wb = wq << 2;
    int h0 = hq << 2;

    const float* pplane = pred + (size_t)sb * (HH * WW);
    const float* tplane = targ + (size_t)(b * SS + s) * (HH * WW);
    float*       oplane = out  + (size_t)sb * (HH * WW);

    // Stage 6 pred rows (h0-1 .. h0+4) x 6 cols (wb-1 .. wb+4) in registers.
    // Rows 1..4 (= h0..h0+3) are always in-image: compile-time rv=true folds
    // the sentinel selects away. Rows 0 and 5 carry the runtime check.
    float v[6][6];
    {
        bool rv0 = (h0 - 1) >= 0;
        bool rv5 = (h0 + 4) < HH;
        int  hc0 = rv0 ? (h0 - 1) : 0;            // clamped, stays in-buffer
        int  hc5 = rv5 ? (h0 + 4) : 0;
        load_row(v[0], pplane + hc0 * WW + wb, wb, rv0);
        #pragma unroll
        for (int r = 1; r <= 4; ++r)
            load_row(v[r], pplane + (h0 + r - 1) * WW + wb, wb, true);
        load_row(v[5], pplane + hc5 * WW + wb, wb, rv5);
    }

    #pragma unroll
    for (int r = 0; r < 4; ++r) {
        float4 t4 = *reinterpret_cast<const float4*>(tplane + (h0 + r) * WW + wb);
        float tv[4] = {t4.x, t4.y, t4.z, t4.w};
        float res[4];
        #pragma unroll
        for (int j = 0; j < 4; ++j) {
            float t = tv[j];
            // Shift 0: (0,0), always valid — initializes best.
            float bestc = v[r + 1][j + 1];
            float bestl = fabsf(t - bestc);
            // Shifts 1..9 in reference order: x=-1..1, y=-1..1 (includes the
            // (0,0) duplicate). Strict < keeps the earliest index => argmin.
            #pragma unroll
            for (int xi = 0; xi < 3; ++xi) {
                #pragma unroll
                for (int yi = 0; yi < 3; ++yi) {
                    float c = v[r + xi][j + yi];
                    float l = fabsf(t - c);
                    if (l < bestl) { bestl = l; bestc = c; }
                }
            }
            res[j] = bestc;
        }
        float4 o4 = make_float4(res[0], res[1], res[2], res[3]);
        *reinterpret_cast<float4*>(oplane + (h0 + r) * WW + wb) = o4;
    }
}

extern "C" void kernel_launch(void* const* d_in, const int* in_sizes, int n_in,
                              void* d_out, int out_size, void* d_ws, size_t ws_size,
                              hipStream_t stream) {
    const float* pred = (const float*)d_in[0];
    const float* targ = (const float*)d_in[1];
    // d_in[2] (mask) unused: reference uses weights = ones.
    float* out = (float*)d_out;

    const int total_threads = SS * BB * (HH / 4) * (WW / 4);  // 1,310,720
    const int block = 256;
    const int grid = (total_threads + block - 1) / block;     // 5,120
    shiftpred_kernel<<<grid, block, 0, stream>>>(pred, targ, out);
}

// Round 4
// 247.546 us; speedup vs baseline: 1.0227x; 1.0227x over previous
//
#include <hip/hip_runtime.h>

// predicted (S,B,H,W) f32, target (B,S,H,W) f32, output (S,B,H,W) f32.
#define SS 10
#define BB 8
#define HH 512
#define WW 512
#define PLANE (HH * WW)
// Sentinel for out-of-image candidates: |t - BIGV| always loses to any valid
// candidate. Finite (no inf-inf NaN); 3e38 - |t| still < FLT_MAX.
#define BIGV 3.0e38f

// 2048 blocks x 256 threads = 8192 waves; each wave owns one full 512-wide row
// per iteration, 5 iterations (planes sb0, sb0+16, ..., sb0+64).
#define NBLK 2048
#define NITER 5

__global__ __launch_bounds__(256, 4) void shiftpred_kernel(
    const float* __restrict__ pred,
    const float* __restrict__ targ,
    float* __restrict__ out)
{
    // XCD-aware bijective swizzle (2048 % 8 == 0): 256 contiguous blocks per
    // XCD so vertically-adjacent rows (halo reuse) share an L2.
    int bid = blockIdx.x;
    int swz = (bid & 7) * (NBLK / 8) + (bid >> 3);

    int wv   = swz * 4 + (int)(threadIdx.x >> 6);   // wave id 0..8191
    int lane = (int)(threadIdx.x & 63);
    int h    = wv & (HH - 1);                       // fixed per wave
    int sb0  = wv >> 9;                             // 0..15
    int w0   = lane << 3;                           // lane owns w0..w0+7

    const bool hm_ok = (h > 0);
    const bool hp_ok = (h < HH - 1);
    const size_t roff  = (size_t)h * WW + w0;
    const size_t roffm = roff - WW;
    const size_t roffp = roff + WW;

    const float4 big4 = make_float4(BIGV, BIGV, BIGV, BIGV);

    auto tile_load = [&](int sb, float4& m0, float4& m1, float4& c0, float4& c1,
                         float4& p0, float4& p1, float4& t0, float4& t1) {
        int s = sb >> 3, b = sb & 7;
        const float* pp = pred + (size_t)sb * PLANE;
        const float* tp = targ + (size_t)(b * SS + s) * PLANE;
        c0 = *reinterpret_cast<const float4*>(pp + roff);
        c1 = *reinterpret_cast<const float4*>(pp + roff + 4);
        if (hm_ok) {  // wave-uniform branch
            m0 = *reinterpret_cast<const float4*>(pp + roffm);
            m1 = *reinterpret_cast<const float4*>(pp + roffm + 4);
        } else { m0 = big4; m1 = big4; }
        if (hp_ok) {
            p0 = *reinterpret_cast<const float4*>(pp + roffp);
            p1 = *reinterpret_cast<const float4*>(pp + roffp + 4);
        } else { p0 = big4; p1 = big4; }
        t0 = *reinterpret_cast<const float4*>(tp + roff);
        t1 = *reinterpret_cast<const float4*>(tp + roff + 4);
    };

    auto tile_compute = [&](int sb, float4 m0, float4 m1, float4 c0, float4 c1,
                            float4 p0, float4 p1, float4 t0, float4 t1) {
        // Strip v[row][0..9] = pred[h+row-1][w0-1 .. w0+8].
        float v[3][10];
        v[0][1] = m0.x; v[0][2] = m0.y; v[0][3] = m0.z; v[0][4] = m0.w;
        v[0][5] = m1.x; v[0][6] = m1.y; v[0][7] = m1.z; v[0][8] = m1.w;
        v[1][1] = c0.x; v[1][2] = c0.y; v[1][3] = c0.z; v[1][4] = c0.w;
        v[1][5] = c1.x; v[1][6] = c1.y; v[1][7] = c1.z; v[1][8] = c1.w;
        v[2][1] = p0.x; v[2][2] = p0.y; v[2][3] = p0.z; v[2][4] = p0.w;
        v[2][5] = p1.x; v[2][6] = p1.y; v[2][7] = p1.z; v[2][8] = p1.w;
        // w-halos live in neighbor lanes' registers: w0-1 = lane-1's q1.w,
        // w0+8 = lane+1's q0.x. Lane 0 / 63 are the true image edges -> BIGV.
        float lm = __shfl_up(m1.w, 1);  float rm = __shfl_down(m0.x, 1);
        float lc = __shfl_up(c1.w, 1);  float rc = __shfl_down(c0.x, 1);
        float lp = __shfl_up(p1.w, 1);  float rp = __shfl_down(p0.x, 1);
        bool e0 = (lane == 0), e63 = (lane == 63);
        v[0][0] = e0 ? BIGV : lm;  v[0][9] = e63 ? BIGV : rm;
        v[1][0] = e0 ? BIGV : lc;  v[1][9] = e63 ? BIGV : rc;
        v[2][0] = e0 ? BIGV : lp;  v[2][9] = e63 ? BIGV : rp;

        float tv[8]  = {t0.x, t0.y, t0.z, t0.w, t1.x, t1.y, t1.z, t1.w};
        float res[8];
        #pragma unroll
        for (int j = 0; j < 8; ++j) {
            float t = tv[j];
            // Shift 0: (0,0), always valid.
            float bestc = v[1][j + 1];
            float bestl = fabsf(t - bestc);
            // Shifts 1..9 in reference order; strict < keeps earliest index.
            #pragma unroll
            for (int xi = 0; xi < 3; ++xi) {
                #pragma unroll
                for (int yi = 0; yi < 3; ++yi) {
                    float c = v[xi][j + yi];
                    float l = fabsf(t - c);
                    if (l < bestl) { bestl = l; bestc = c; }
                }
            }
            res[j] = bestc;
        }
        float* op = out + (size_t)sb * PLANE + roff;
        *reinterpret_cast<float4*>(op)     = make_float4(res[0], res[1], res[2], res[3]);
        *reinterpret_cast<float4*>(op + 4) = make_float4(res[4], res[5], res[6], res[7]);
    };

    float4 cm0, cm1, cc0, cc1, cp0, cp1, ct0, ct1;   // current tile
    float4 nm0, nm1, nc0, nc1, np0, np1, nt0, nt1;   // prefetched next tile

    tile_load(sb0, cm0, cm1, cc0, cc1, cp0, cp1, ct0, ct1);
    #pragma unroll
    for (int it = 0; it < NITER; ++it) {
        int sb = sb0 + (it << 4);
        if (it < NITER - 1)   // compile-time under full unroll
            tile_load(sb0 + ((it + 1) << 4),
                      nm0, nm1, nc0, nc1, np0, np1, nt0, nt1);
        tile_compute(sb, cm0, cm1, cc0, cc1, cp0, cp1, ct0, ct1);
        // SSA renaming elides these copies under full unroll.
        cm0 = nm0; cm1 = nm1; cc0 = nc0; cc1 = nc1;
        cp0 = np0; cp1 = np1; ct0 = nt0; ct1 = nt1;
    }
}

extern "C" void kernel_launch(void* const* d_in, const int* in_sizes, int n_in,
                              void* d_out, int out_size, void* d_ws, size_t ws_size,
                              hipStream_t stream) {
    const float* pred = (const float*)d_in[0];
    const float* targ = (const float*)d_in[1];
    // d_in[2] (mask) unused: reference uses weights = ones.
    float* out = (float*)d_out;
    shiftpred_kernel<<<NBLK, 256, 0, stream>>>(pred, targ, out);
}